// Round 4
// baseline (205.848 us; speedup 1.0000x reference)
//
#include <hip/hip_runtime.h>
#include <hip/hip_bf16.h>

// Problem constants
static constexpr int kB   = 8;
static constexpr int kP   = 196;
static constexpr int kL   = 80;
static constexpr int kD1  = 2048;
static constexpr int kD2  = 300;
static constexpr int kD2p = 320;       // K of p2 padded to multiple of 32
static constexpr int kATT = 1024;
static constexpr int kM   = kB * kP;   // 1568 rows of p1
static constexpr int kR2  = kB * kL;   // 640 rows of p2
static constexpr int kASplit = 4;      // alpha: a-dim split across blocks
static constexpr int kAChunk = kATT / kASplit;   // 256

// tanh(x) = 1 - 2/(exp2(x*2*log2(e)) + 1)   (exact at 0, saturates correctly)
__device__ __forceinline__ float fast_tanh(float x) {
    float e = __builtin_amdgcn_exp2f(x * 2.8853900817779268f);
    return 1.0f - 2.0f * __builtin_amdgcn_rcpf(e + 1.0f);
}

// fp32 -> bf16 round-to-nearest-even (inputs are finite; skip NaN path)
__device__ __forceinline__ unsigned short f2bf(float x) {
    union { float f; unsigned int u; } c; c.f = x;
    unsigned int r = c.u + 0x7fffu + ((c.u >> 16) & 1u);
    return (unsigned short)(r >> 16);
}

typedef __attribute__((ext_vector_type(8))) short  bf16x8;
typedef __attribute__((ext_vector_type(4))) float  f32x4;

__device__ __forceinline__ void load_lds16(const void* g, void* l) {
    __builtin_amdgcn_global_load_lds(
        (const __attribute__((address_space(1))) void*)g,
        (__attribute__((address_space(3))) void*)l, 16, 0, 0);
}

// ---------------------------------------------------------------------------
// Cast x1 (kM x kD1) and W1 (kATT x kD1) fp32 -> bf16, vectorized 4-wide.
// ---------------------------------------------------------------------------
__global__ __launch_bounds__(256) void cast_kernel(
        const float* __restrict__ x1, unsigned short* __restrict__ x1b,
        const float* __restrict__ W1, unsigned short* __restrict__ W1b) {
    const int n1 = kM * kD1 / 4;
    const int n2 = kATT * kD1 / 4;
    int i = blockIdx.x * 256 + threadIdx.x;
    if (i < n1) {
        float4 f = ((const float4*)x1)[i];
        ushort4 o = { f2bf(f.x), f2bf(f.y), f2bf(f.z), f2bf(f.w) };
        ((ushort4*)x1b)[i] = o;
    } else if (i - n1 < n2) {
        int j = i - n1;
        float4 f = ((const float4*)W1)[j];
        ushort4 o = { f2bf(f.x), f2bf(f.y), f2bf(f.z), f2bf(f.w) };
        ((ushort4*)W1b)[j] = o;
    }
}

// ---------------------------------------------------------------------------
// Cast+pad x2 (kR2 x 300 -> kR2 x 320) and W2 (kATT x 300 -> kATT x 320).
// ---------------------------------------------------------------------------
__global__ __launch_bounds__(256) void cast_pad_kernel(
        const float* __restrict__ x2, unsigned short* __restrict__ x2b,
        const float* __restrict__ W2, unsigned short* __restrict__ W2b) {
    const int n1 = kR2 * kD2p;
    const int n2 = kATT * kD2p;
    int idx = blockIdx.x * 256 + threadIdx.x;
    if (idx < n1) {
        int r = idx / kD2p, c = idx - r * kD2p;
        x2b[idx] = (c < kD2) ? f2bf(x2[(size_t)r * kD2 + c]) : (unsigned short)0;
    } else if (idx - n1 < n2) {
        int j = idx - n1;
        int r = j / kD2p, c = j - r * kD2p;
        W2b[j] = (c < kD2) ? f2bf(W2[(size_t)r * kD2 + c]) : (unsigned short)0;
    }
}

// ---------------------------------------------------------------------------
// v[a] = sum_c wt[c]*Wh[c,a];  beta = dot(wt,bh) + bt
// ---------------------------------------------------------------------------
__global__ __launch_bounds__(256) void vbeta_kernel(
        const float* __restrict__ Wh, const float* __restrict__ wt,
        const float* __restrict__ bh, const float* __restrict__ bt,
        float* __restrict__ v, float* __restrict__ beta) {
    const int a  = blockIdx.x * 256 + threadIdx.x;
    const int c0 = blockIdx.y * 64;
    float acc = 0.0f;
    #pragma unroll 8
    for (int c = c0; c < c0 + 64; ++c)
        acc = fmaf(wt[c], Wh[(size_t)c * kATT + a], acc);
    atomicAdd(&v[a], acc);

    if (blockIdx.x == 0 && threadIdx.x < 64) {
        int c = c0 + threadIdx.x;
        float pb = wt[c] * bh[c];
        #pragma unroll
        for (int off = 32; off > 0; off >>= 1)
            pb += __shfl_down(pb, off, 64);
        if (threadIdx.x == 0) {
            if (blockIdx.y == 0) pb += bt[0];
            atomicAdd(beta, pb);
        }
    }
}

// ---------------------------------------------------------------------------
// C[m,n] = sum_k A[m,k]*B[n,k]  bf16 MFMA, 64x64 tile, BK=32, 4 waves.
// ---------------------------------------------------------------------------
template<int KT>
__global__ __launch_bounds__(256) void gemm_bt_mfma(
        const unsigned short* __restrict__ Ab,
        const unsigned short* __restrict__ Bb,
        float* __restrict__ Co, int M) {
    __shared__ unsigned short As[64 * 32];   // 4 KB, row stride 64 B
    __shared__ unsigned short Bs[64 * 32];   // 4 KB
    const int m0   = blockIdx.x * 64;
    const int n0   = blockIdx.y * 64;
    const int tid  = threadIdx.x;
    const int lane = tid & 63;
    const int wv   = tid >> 6;
    const int mh   = (wv >> 1) * 32;
    const int nh   = (wv & 1) * 32;

    const int srow = tid >> 2;
    const int skc  = (tid & 3) * 8;
    const int arow = min(m0 + srow, M - 1);  // clamp ragged M edge
    const int brow = n0 + srow;              // N exact

    f32x4 acc[2][2] = {};
    for (int k0 = 0; k0 < KT; k0 += 32) {
        load_lds16(Ab + (size_t)arow * KT + k0 + skc, (char*)As + tid * 16);
        load_lds16(Bb + (size_t)brow * KT + k0 + skc, (char*)Bs + tid * 16);
        __syncthreads();

        bf16x8 af[2], bf[2];
        #pragma unroll
        for (int i = 0; i < 2; ++i) {
            int r = mh + i * 16 + (lane & 15);
            af[i] = *(const bf16x8*)((const char*)As + r * 64 + (lane >> 4) * 16);
        }
        #pragma unroll
        for (int j = 0; j < 2; ++j) {
            int r = nh + j * 16 + (lane & 15);
            bf[j] = *(const bf16x8*)((const char*)Bs + r * 64 + (lane >> 4) * 16);
        }
        #pragma unroll
        for (int i = 0; i < 2; ++i)
            #pragma unroll
            for (int j = 0; j < 2; ++j)
                acc[i][j] = __builtin_amdgcn_mfma_f32_16x16x32_bf16(
                                af[i], bf[j], acc[i][j], 0, 0, 0);
        __syncthreads();
    }

    // C/D layout: col = lane&15, row = (lane>>4)*4 + reg   [m89/m91 verified]
    #pragma unroll
    for (int i = 0; i < 2; ++i)
        #pragma unroll
        for (int j = 0; j < 2; ++j)
            #pragma unroll
            for (int r = 0; r < 4; ++r) {
                int m = m0 + mh + i * 16 + (lane >> 4) * 4 + r;
                int n = n0 + nh + j * 16 + (lane & 15);
                if (m < M) Co[(size_t)m * kATT + n] = acc[i][j][r];
            }
}

// ---------------------------------------------------------------------------
// alpha partial: for a-chunk `as`, accumulate
//   out[b,l,p] += sum_{a in chunk} v[a]*tanh(p1[b,p,a]*p2[b,l,a])  (+beta once)
// grid (13, 5, kB*kASplit). out must be pre-zeroed.
// ---------------------------------------------------------------------------
__global__ __launch_bounds__(256) void alpha_kernel(
        const float* __restrict__ p1, const float* __restrict__ p2,
        const float* __restrict__ v, const float* __restrict__ beta,
        float* __restrict__ out) {
    __shared__ float vs[kAChunk];            // 1 KB
    __shared__ float p1s[16 * 132];          // 8.25 KB, stride 132
    __shared__ float p2s[16 * 132];
    const int bz    = blockIdx.z;
    const int b     = bz >> 2;               // kASplit = 4
    const int as    = bz & 3;
    const int aBase = as * kAChunk;
    const int p0    = blockIdx.x * 16;
    const int l0    = blockIdx.y * 16;
    const int tid   = threadIdx.x;
    const int tp    = tid & 15;              // p across lanes -> coalesced
    const int tl    = tid >> 4;

    for (int i = tid; i < kAChunk; i += 256) vs[i] = v[aBase + i];

    float acc = 0.0f;
    #pragma unroll
    for (int c = 0; c < kAChunk / 128; ++c) {
        const int a0 = aBase + c * 128;
        __syncthreads();
        #pragma unroll
        for (int t = 0; t < 2; ++t) {
            int idx = tid + t * 256;         // 0..511 float4 slots
            int row = idx >> 5;              // 0..15
            int c4  = (idx & 31) * 4;        // 0..124
            int gr1 = min(b * kP + p0 + row, kM - 1);   // clamp ragged p edge
            float4 u = *(const float4*)(p1 + (size_t)gr1 * kATT + a0 + c4);
            *(float4*)&p1s[row * 132 + c4] = u;
            int gr2 = b * kL + l0 + row;
            float4 w = *(const float4*)(p2 + (size_t)gr2 * kATT + a0 + c4);
            *(float4*)&p2s[row * 132 + c4] = w;
        }
        __syncthreads();
        #pragma unroll
        for (int a4 = 0; a4 < 32; ++a4) {
            float4 u  = *(const float4*)&p1s[tp * 132 + a4 * 4];
            float4 w  = *(const float4*)&p2s[tl * 132 + a4 * 4];
            float4 vv = *(const float4*)&vs[c * 128 + a4 * 4];
            acc = fmaf(vv.x, fast_tanh(u.x * w.x), acc);
            acc = fmaf(vv.y, fast_tanh(u.y * w.y), acc);
            acc = fmaf(vv.z, fast_tanh(u.z * w.z), acc);
            acc = fmaf(vv.w, fast_tanh(u.w * w.w), acc);
        }
    }
    int p = p0 + tp;
    if (p < kP) {
        if (as == 0) acc += beta[0];         // beta added exactly once
        atomicAdd(&out[((size_t)b * kL + l0 + tl) * kP + p], acc);
    }
}

// ---------------------------------------------------------------------------
extern "C" void kernel_launch(void* const* d_in, const int* in_sizes, int n_in,
                              void* d_out, int out_size, void* d_ws, size_t ws_size,
                              hipStream_t stream) {
    const float* x1 = (const float*)d_in[0];
    const float* x2 = (const float*)d_in[1];
    const float* W1 = (const float*)d_in[2];
    const float* W2 = (const float*)d_in[3];
    const float* Wh = (const float*)d_in[4];
    const float* bh = (const float*)d_in[5];
    const float* wt = (const float*)d_in[6];
    const float* bt = (const float*)d_in[7];
    float* out = (float*)d_out;

    // workspace (floats then bf16):
    // v[1024] | beta pad -> 1088 | p2w[640*1024] | p1w[1568*1024]
    // | x1b[kM*kD1] | W1b[kATT*kD1] | x2b[kR2*320] | W2b[kATT*320]   (~20.7 MB)
    float* ws   = (float*)d_ws;
    float* v    = ws;
    float* beta = ws + 1024;
    float* p2w  = ws + 1088;
    float* p1w  = p2w + (size_t)kR2 * kATT;
    unsigned short* x1b = (unsigned short*)(p1w + (size_t)kM * kATT);
    unsigned short* W1b = x1b + (size_t)kM * kD1;
    unsigned short* x2b = W1b + (size_t)kATT * kD1;
    unsigned short* W2b = x2b + (size_t)kR2 * kD2p;

    hipMemsetAsync(ws, 0, 1088 * sizeof(float), stream);
    hipMemsetAsync(out, 0, (size_t)out_size * sizeof(float), stream);

    {   // cast x1 + W1 to bf16
        int n4 = (kM * kD1 + kATT * kD1) / 4;
        cast_kernel<<<dim3((n4 + 255) / 256), 256, 0, stream>>>(x1, x1b, W1, W1b);
    }
    {   // cast + pad x2 + W2 to bf16 (K 300 -> 320)
        int n = (kR2 + kATT) * kD2p;
        cast_pad_kernel<<<dim3((n + 255) / 256), 256, 0, stream>>>(x2, x2b, W2, W2b);
    }
    vbeta_kernel<<<dim3(4, 16), 256, 0, stream>>>(Wh, wt, bh, bt, v, beta);
    gemm_bt_mfma<kD2p><<<dim3(kR2 / 64, kATT / 64), 256, 0, stream>>>(x2b, W2b, p2w, kR2);
    gemm_bt_mfma<kD1><<<dim3((kM + 63) / 64, kATT / 64), 256, 0, stream>>>(x1b, W1b, p1w, kM);
    alpha_kernel<<<dim3((kP + 15) / 16, kL / 16, kB * kASplit), 256, 0, stream>>>(
        p1w, p2w, v, beta, out);
}

// Round 5
// 201.316 us; speedup vs baseline: 1.0225x; 1.0225x over previous
//
#include <hip/hip_runtime.h>
#include <hip/hip_bf16.h>

// Problem constants
static constexpr int kB   = 8;
static constexpr int kP   = 196;
static constexpr int kL   = 80;
static constexpr int kD1  = 2048;
static constexpr int kD2  = 300;
static constexpr int kD2p = 320;       // K of p2 padded to multiple of 32
static constexpr int kATT = 1024;
static constexpr int kM   = kB * kP;   // 1568 rows of p1
static constexpr int kR2  = kB * kL;   // 640 rows of p2
static constexpr int kASplit = 4;      // alpha: a-dim split across blocks
static constexpr int kAChunk = kATT / kASplit;   // 256 == alpha block size

static constexpr float kTanhScale = 2.8853900817779268f;  // 2*log2(e)

// fp32 -> bf16 round-to-nearest-even (inputs are finite; skip NaN path)
__device__ __forceinline__ unsigned short f2bf(float x) {
    union { float f; unsigned int u; } c; c.f = x;
    unsigned int r = c.u + 0x7fffu + ((c.u >> 16) & 1u);
    return (unsigned short)(r >> 16);
}

typedef __attribute__((ext_vector_type(8))) short  bf16x8;
typedef __attribute__((ext_vector_type(4))) float  f32x4;

__device__ __forceinline__ void load_lds16(const void* g, void* l) {
    __builtin_amdgcn_global_load_lds(
        (const __attribute__((address_space(1))) void*)g,
        (__attribute__((address_space(3))) void*)l, 16, 0, 0);
}

// ---------------------------------------------------------------------------
// Cast x1 (kM x kD1) and W1 (kATT x kD1) fp32 -> bf16, vectorized 4-wide.
// ---------------------------------------------------------------------------
__global__ __launch_bounds__(256) void cast_kernel(
        const float* __restrict__ x1, unsigned short* __restrict__ x1b,
        const float* __restrict__ W1, unsigned short* __restrict__ W1b) {
    const int n1 = kM * kD1 / 4;
    const int n2 = kATT * kD1 / 4;
    int i = blockIdx.x * 256 + threadIdx.x;
    if (i < n1) {
        float4 f = ((const float4*)x1)[i];
        ushort4 o = { f2bf(f.x), f2bf(f.y), f2bf(f.z), f2bf(f.w) };
        ((ushort4*)x1b)[i] = o;
    } else if (i - n1 < n2) {
        int j = i - n1;
        float4 f = ((const float4*)W1)[j];
        ushort4 o = { f2bf(f.x), f2bf(f.y), f2bf(f.z), f2bf(f.w) };
        ((ushort4*)W1b)[j] = o;
    }
}

// ---------------------------------------------------------------------------
// Cast+pad x2 (kR2 x 300 -> kR2 x 320) and W2 (kATT x 300 -> kATT x 320).
// ---------------------------------------------------------------------------
__global__ __launch_bounds__(256) void cast_pad_kernel(
        const float* __restrict__ x2, unsigned short* __restrict__ x2b,
        const float* __restrict__ W2, unsigned short* __restrict__ W2b) {
    const int n1 = kR2 * kD2p;
    const int n2 = kATT * kD2p;
    int idx = blockIdx.x * 256 + threadIdx.x;
    if (idx < n1) {
        int r = idx / kD2p, c = idx - r * kD2p;
        x2b[idx] = (c < kD2) ? f2bf(x2[(size_t)r * kD2 + c]) : (unsigned short)0;
    } else if (idx - n1 < n2) {
        int j = idx - n1;
        int r = j / kD2p, c = j - r * kD2p;
        W2b[j] = (c < kD2) ? f2bf(W2[(size_t)r * kD2 + c]) : (unsigned short)0;
    }
}

// ---------------------------------------------------------------------------
// v[a] = sum_c wt[c]*Wh[c,a];  beta = dot(wt,bh) + bt
// ---------------------------------------------------------------------------
__global__ __launch_bounds__(256) void vbeta_kernel(
        const float* __restrict__ Wh, const float* __restrict__ wt,
        const float* __restrict__ bh, const float* __restrict__ bt,
        float* __restrict__ v, float* __restrict__ beta) {
    const int a  = blockIdx.x * 256 + threadIdx.x;
    const int c0 = blockIdx.y * 64;
    float acc = 0.0f;
    #pragma unroll 8
    for (int c = c0; c < c0 + 64; ++c)
        acc = fmaf(wt[c], Wh[(size_t)c * kATT + a], acc);
    atomicAdd(&v[a], acc);

    if (blockIdx.x == 0 && threadIdx.x < 64) {
        int c = c0 + threadIdx.x;
        float pb = wt[c] * bh[c];
        #pragma unroll
        for (int off = 32; off > 0; off >>= 1)
            pb += __shfl_down(pb, off, 64);
        if (threadIdx.x == 0) {
            if (blockIdx.y == 0) pb += bt[0];
            atomicAdd(beta, pb);
        }
    }
}

// ---------------------------------------------------------------------------
// C[m,n] = scale * sum_k A[m,k]*B[n,k]  bf16 MFMA, 64x64 tile, BK=32, 4 waves.
// ---------------------------------------------------------------------------
template<int KT>
__global__ __launch_bounds__(256) void gemm_bt_mfma(
        const unsigned short* __restrict__ Ab,
        const unsigned short* __restrict__ Bb,
        float* __restrict__ Co, int M, float scale) {
    __shared__ unsigned short As[64 * 32];   // 4 KB, row stride 64 B
    __shared__ unsigned short Bs[64 * 32];   // 4 KB
    const int m0   = blockIdx.x * 64;
    const int n0   = blockIdx.y * 64;
    const int tid  = threadIdx.x;
    const int lane = tid & 63;
    const int wv   = tid >> 6;
    const int mh   = (wv >> 1) * 32;
    const int nh   = (wv & 1) * 32;

    const int srow = tid >> 2;
    const int skc  = (tid & 3) * 8;
    const int arow = min(m0 + srow, M - 1);  // clamp ragged M edge
    const int brow = n0 + srow;              // N exact

    f32x4 acc[2][2] = {};
    for (int k0 = 0; k0 < KT; k0 += 32) {
        load_lds16(Ab + (size_t)arow * KT + k0 + skc, (char*)As + tid * 16);
        load_lds16(Bb + (size_t)brow * KT + k0 + skc, (char*)Bs + tid * 16);
        __syncthreads();

        bf16x8 af[2], bf[2];
        #pragma unroll
        for (int i = 0; i < 2; ++i) {
            int r = mh + i * 16 + (lane & 15);
            af[i] = *(const bf16x8*)((const char*)As + r * 64 + (lane >> 4) * 16);
        }
        #pragma unroll
        for (int j = 0; j < 2; ++j) {
            int r = nh + j * 16 + (lane & 15);
            bf[j] = *(const bf16x8*)((const char*)Bs + r * 64 + (lane >> 4) * 16);
        }
        #pragma unroll
        for (int i = 0; i < 2; ++i)
            #pragma unroll
            for (int j = 0; j < 2; ++j)
                acc[i][j] = __builtin_amdgcn_mfma_f32_16x16x32_bf16(
                                af[i], bf[j], acc[i][j], 0, 0, 0);
        __syncthreads();
    }

    // C/D layout: col = lane&15, row = (lane>>4)*4 + reg   [m89/m91 verified]
    #pragma unroll
    for (int i = 0; i < 2; ++i)
        #pragma unroll
        for (int j = 0; j < 2; ++j)
            #pragma unroll
            for (int r = 0; r < 4; ++r) {
                int m = m0 + mh + i * 16 + (lane >> 4) * 4 + r;
                int n = n0 + nh + j * 16 + (lane & 15);
                if (m < M) Co[(size_t)m * kATT + n] = scale * acc[i][j][r];
            }
}

// ---------------------------------------------------------------------------
// alpha partial, barrier-free streaming version.
//   p1 is PRE-SCALED by 2*log2(e), so tanh(x) = 1 - 2*rcp(exp2(u*w)+1) and
//   sum_a v*tanh = sumV_chunk - 2 * sum_a v*rcp(exp2(u*w)+1).
// Each thread owns one (p,l) output and streams its a-chunk straight from
// global (L1/L2 serve the broadcast rows); only v is staged in LDS.
// grid (13, 5, kB*kASplit), block 256. out pre-zeroed; beta added by as==0.
// ---------------------------------------------------------------------------
__global__ __launch_bounds__(256) void alpha_kernel(
        const float* __restrict__ p1, const float* __restrict__ p2,
        const float* __restrict__ v, const float* __restrict__ beta,
        float* __restrict__ out) {
    __shared__ float vs[kAChunk];            // 1 KB
    __shared__ float vred[4];
    const int bz    = blockIdx.z;
    const int b     = bz >> 2;               // kASplit = 4
    const int as    = bz & 3;
    const int aBase = as * kAChunk;
    const int p0    = blockIdx.x * 16;
    const int l0    = blockIdx.y * 16;
    const int tid   = threadIdx.x;
    const int tp    = tid & 15;
    const int tl    = tid >> 4;

    // stage v chunk + compute its sum (once per block)
    float myv = v[aBase + tid];              // kAChunk == blockDim.x
    vs[tid] = myv;
    float s = myv;
    #pragma unroll
    for (int off = 32; off > 0; off >>= 1)
        s += __shfl_down(s, off, 64);
    if ((tid & 63) == 0) vred[tid >> 6] = s;
    __syncthreads();
    const float sumV = vred[0] + vred[1] + vred[2] + vred[3];

    const int p   = p0 + tp;                 // may exceed kP-1 on last tile
    const int gr1 = b * kP + min(p, kP - 1); // clamped read row
    const int gr2 = b * kL + l0 + tl;        // exact
    const float* pu = p1 + (size_t)gr1 * kATT + aBase;
    const float* pw = p2 + (size_t)gr2 * kATT + aBase;

    float acc = 0.0f;                        // sum of v * rcp(exp2(u*w)+1)
    #pragma unroll 4
    for (int a4 = 0; a4 < kAChunk / 4; ++a4) {
        float4 u  = *(const float4*)(pu + a4 * 4);
        float4 w  = *(const float4*)(pw + a4 * 4);
        float4 vv = *(const float4*)&vs[a4 * 4];
        acc = fmaf(vv.x, __builtin_amdgcn_rcpf(__builtin_amdgcn_exp2f(u.x * w.x) + 1.0f), acc);
        acc = fmaf(vv.y, __builtin_amdgcn_rcpf(__builtin_amdgcn_exp2f(u.y * w.y) + 1.0f), acc);
        acc = fmaf(vv.z, __builtin_amdgcn_rcpf(__builtin_amdgcn_exp2f(u.z * w.z) + 1.0f), acc);
        acc = fmaf(vv.w, __builtin_amdgcn_rcpf(__builtin_amdgcn_exp2f(u.w * w.w) + 1.0f), acc);
    }
    float res = sumV - 2.0f * acc;
    if (as == 0) res += beta[0];
    if (p < kP)
        atomicAdd(&out[((size_t)b * kL + l0 + tl) * kP + p], res);
}

// ---------------------------------------------------------------------------
extern "C" void kernel_launch(void* const* d_in, const int* in_sizes, int n_in,
                              void* d_out, int out_size, void* d_ws, size_t ws_size,
                              hipStream_t stream) {
    const float* x1 = (const float*)d_in[0];
    const float* x2 = (const float*)d_in[1];
    const float* W1 = (const float*)d_in[2];
    const float* W2 = (const float*)d_in[3];
    const float* Wh = (const float*)d_in[4];
    const float* bh = (const float*)d_in[5];
    const float* wt = (const float*)d_in[6];
    const float* bt = (const float*)d_in[7];
    float* out = (float*)d_out;

    // workspace (floats then bf16):
    // v[1024] | beta pad -> 1088 | p2w[640*1024] | p1w[1568*1024]
    // | x1b[kM*kD1] | W1b[kATT*kD1] | x2b[kR2*320] | W2b[kATT*320]   (~20.7 MB)
    float* ws   = (float*)d_ws;
    float* v    = ws;
    float* beta = ws + 1024;
    float* p2w  = ws + 1088;
    float* p1w  = p2w + (size_t)kR2 * kATT;
    unsigned short* x1b = (unsigned short*)(p1w + (size_t)kM * kATT);
    unsigned short* W1b = x1b + (size_t)kM * kD1;
    unsigned short* x2b = W1b + (size_t)kATT * kD1;
    unsigned short* W2b = x2b + (size_t)kR2 * kD2p;

    hipMemsetAsync(ws, 0, 1088 * sizeof(float), stream);
    hipMemsetAsync(out, 0, (size_t)out_size * sizeof(float), stream);

    {   // cast x1 + W1 to bf16
        int n4 = (kM * kD1 + kATT * kD1) / 4;
        cast_kernel<<<dim3((n4 + 255) / 256), 256, 0, stream>>>(x1, x1b, W1, W1b);
    }
    {   // cast + pad x2 + W2 to bf16 (K 300 -> 320)
        int n = (kR2 + kATT) * kD2p;
        cast_pad_kernel<<<dim3((n + 255) / 256), 256, 0, stream>>>(x2, x2b, W2, W2b);
    }
    vbeta_kernel<<<dim3(4, 16), 256, 0, stream>>>(Wh, wt, bh, bt, v, beta);
    gemm_bt_mfma<kD2p><<<dim3(kR2 / 64, kATT / 64), 256, 0, stream>>>(
        x2b, W2b, p2w, kR2, 1.0f);
    gemm_bt_mfma<kD1><<<dim3((kM + 63) / 64, kATT / 64), 256, 0, stream>>>(
        x1b, W1b, p1w, kM, kTanhScale);      // p1 pre-scaled for tanh
    alpha_kernel<<<dim3((kP + 15) / 16, kL / 16, kB * kASplit), 256, 0, stream>>>(
        p1w, p2w, v, beta, out);
}

// Round 6
// 161.131 us; speedup vs baseline: 1.2775x; 1.2494x over previous
//
#include <hip/hip_runtime.h>
#include <hip/hip_bf16.h>

// Problem constants
static constexpr int kB   = 8;
static constexpr int kP   = 196;
static constexpr int kL   = 80;
static constexpr int kD1  = 2048;
static constexpr int kD2  = 300;
static constexpr int kD2p = 320;       // K of p2 padded to multiple of 64
static constexpr int kATT = 1024;
static constexpr int kM   = kB * kP;   // 1568 rows of p1
static constexpr int kR2  = kB * kL;   // 640 rows of p2
static constexpr int kASplit = 8;      // alpha: a-dim split across blocks
static constexpr int kAChunk = kATT / kASplit;   // 128
static constexpr int kLPer   = 5;      // l-values per thread (16 groups x 5 = 80)

static constexpr float kTanhScale = 2.8853900817779268f;  // 2*log2(e)

// fp32 -> bf16 round-to-nearest-even
__device__ __forceinline__ unsigned short f2bf(float x) {
    union { float f; unsigned int u; } c; c.f = x;
    unsigned int r = c.u + 0x7fffu + ((c.u >> 16) & 1u);
    return (unsigned short)(r >> 16);
}

typedef __attribute__((ext_vector_type(8))) short  bf16x8;
typedef __attribute__((ext_vector_type(4))) float  f32x4;

__device__ __forceinline__ void load_lds16(const void* g, void* l) {
    __builtin_amdgcn_global_load_lds(
        (const __attribute__((address_space(1))) void*)g,
        (__attribute__((address_space(3))) void*)l, 16, 0, 0);
}

// ---------------------------------------------------------------------------
// Fused casts: x1,W1 fp32->bf16 (float4-wide) ; x2,W2 fp32->bf16 pad K 300->320
// ---------------------------------------------------------------------------
__global__ __launch_bounds__(256) void cast_all_kernel(
        const float* __restrict__ x1, unsigned short* __restrict__ x1b,
        const float* __restrict__ W1, unsigned short* __restrict__ W1b,
        const float* __restrict__ x2, unsigned short* __restrict__ x2b,
        const float* __restrict__ W2, unsigned short* __restrict__ W2b) {
    const int n4a = kM * kD1 / 4;          // x1 float4s
    const int n4b = kATT * kD1 / 4;        // W1 float4s
    const int n1  = kR2 * kD2p;            // x2b elems (padded)
    const int n2  = kATT * kD2p;           // W2b elems (padded)
    int i = blockIdx.x * 256 + threadIdx.x;
    if (i < n4a) {
        float4 f = ((const float4*)x1)[i];
        ushort4 o = { f2bf(f.x), f2bf(f.y), f2bf(f.z), f2bf(f.w) };
        ((ushort4*)x1b)[i] = o;
    } else if ((i -= n4a) < n4b) {
        float4 f = ((const float4*)W1)[i];
        ushort4 o = { f2bf(f.x), f2bf(f.y), f2bf(f.z), f2bf(f.w) };
        ((ushort4*)W1b)[i] = o;
    } else if ((i -= n4b) < n1) {
        int r = i / kD2p, c = i - r * kD2p;
        x2b[i] = (c < kD2) ? f2bf(x2[(size_t)r * kD2 + c]) : (unsigned short)0;
    } else if ((i -= n1) < n2) {
        int r = i / kD2p, c = i - r * kD2p;
        W2b[i] = (c < kD2) ? f2bf(W2[(size_t)r * kD2 + c]) : (unsigned short)0;
    }
}

// ---------------------------------------------------------------------------
// v[a] = sum_c wt[c]*Wh[c,a];  beta = dot(wt,bh) + bt   (v/beta pre-zeroed)
// ---------------------------------------------------------------------------
__global__ __launch_bounds__(256) void vbeta_kernel(
        const float* __restrict__ Wh, const float* __restrict__ wt,
        const float* __restrict__ bh, const float* __restrict__ bt,
        float* __restrict__ v, float* __restrict__ beta) {
    const int a  = blockIdx.x * 256 + threadIdx.x;
    const int c0 = blockIdx.y * 64;
    float acc = 0.0f;
    #pragma unroll 8
    for (int c = c0; c < c0 + 64; ++c)
        acc = fmaf(wt[c], Wh[(size_t)c * kATT + a], acc);
    atomicAdd(&v[a], acc);

    if (blockIdx.x == 0 && threadIdx.x < 64) {
        int c = c0 + threadIdx.x;
        float pb = wt[c] * bh[c];
        #pragma unroll
        for (int off = 32; off > 0; off >>= 1)
            pb += __shfl_down(pb, off, 64);
        if (threadIdx.x == 0) {
            if (blockIdx.y == 0) pb += bt[0];
            atomicAdd(beta, pb);
        }
    }
}

// ---------------------------------------------------------------------------
// Fused GEMMs (both C = scale * A·B^T, N = 1024): blocks [0,160) do p2
// (M=640, K=320), blocks [160,560) do p1 (M=1568, K=2048, scale=2log2e).
// 64x64 tile, BK=64 (16 KB LDS, half the barriers of BK=32), 4 waves,
// each wave a 32x32 quadrant as 2x2 MFMA 16x16x32 tiles, 2 k-subiters.
// ---------------------------------------------------------------------------
static constexpr int kP2Blocks = (kR2 / 64) * (kATT / 64);   // 160
static constexpr int kP1Blocks = ((kM + 63) / 64) * (kATT / 64); // 400

__global__ __launch_bounds__(256) void gemm_all_kernel(
        const unsigned short* __restrict__ x2b, const unsigned short* __restrict__ W2b,
        float* __restrict__ p2w,
        const unsigned short* __restrict__ x1b, const unsigned short* __restrict__ W1b,
        float* __restrict__ p1w) {
    __shared__ unsigned short As[64 * 64];   // 8 KB, row = 64 k-elems (128 B)
    __shared__ unsigned short Bs[64 * 64];   // 8 KB

    const unsigned short *Ab, *Bb;
    float* Co; int M, K, mx, nx; float scale;
    {
        int bid = blockIdx.x;
        if (bid < kP2Blocks) {
            Ab = x2b; Bb = W2b; Co = p2w; M = kR2; K = kD2p; scale = 1.0f;
            mx = bid % (kR2 / 64); nx = bid / (kR2 / 64);
        } else {
            int l = bid - kP2Blocks;
            Ab = x1b; Bb = W1b; Co = p1w; M = kM; K = kD1; scale = kTanhScale;
            mx = l % ((kM + 63) / 64); nx = l / ((kM + 63) / 64);
        }
    }
    const int m0   = mx * 64;
    const int n0   = nx * 64;
    const int tid  = threadIdx.x;
    const int lane = tid & 63;
    const int wv   = tid >> 6;
    const int mh   = (wv >> 1) * 32;
    const int nh   = (wv & 1) * 32;

    // staging: thread stages chunks tid and tid+256 (16 B each)
    const int row0 = tid >> 3,        ko0 = (tid & 7) * 8;
    const int row1 = (tid + 256) >> 3, ko1 = (tid & 7) * 8;
    const int ar0 = min(m0 + row0, M - 1), ar1 = min(m0 + row1, M - 1);
    const int br0 = n0 + row0,            br1 = n0 + row1;

    f32x4 acc[2][2] = {};
    for (int k0 = 0; k0 < K; k0 += 64) {
        load_lds16(Ab + (size_t)ar0 * K + k0 + ko0, (char*)As + tid * 16);
        load_lds16(Ab + (size_t)ar1 * K + k0 + ko1, (char*)As + (tid + 256) * 16);
        load_lds16(Bb + (size_t)br0 * K + k0 + ko0, (char*)Bs + tid * 16);
        load_lds16(Bb + (size_t)br1 * K + k0 + ko1, (char*)Bs + (tid + 256) * 16);
        __syncthreads();

        #pragma unroll
        for (int kk = 0; kk < 2; ++kk) {
            bf16x8 af[2], bf[2];
            #pragma unroll
            for (int i = 0; i < 2; ++i) {
                int r = mh + i * 16 + (lane & 15);
                af[i] = *(const bf16x8*)((const char*)As + r * 128 + kk * 64 + (lane >> 4) * 16);
            }
            #pragma unroll
            for (int j = 0; j < 2; ++j) {
                int r = nh + j * 16 + (lane & 15);
                bf[j] = *(const bf16x8*)((const char*)Bs + r * 128 + kk * 64 + (lane >> 4) * 16);
            }
            #pragma unroll
            for (int i = 0; i < 2; ++i)
                #pragma unroll
                for (int j = 0; j < 2; ++j)
                    acc[i][j] = __builtin_amdgcn_mfma_f32_16x16x32_bf16(
                                    af[i], bf[j], acc[i][j], 0, 0, 0);
        }
        __syncthreads();
    }

    // C/D layout: col = lane&15, row = (lane>>4)*4 + reg   [m89/m91 verified]
    #pragma unroll
    for (int i = 0; i < 2; ++i)
        #pragma unroll
        for (int j = 0; j < 2; ++j)
            #pragma unroll
            for (int r = 0; r < 4; ++r) {
                int m = m0 + mh + i * 16 + (lane >> 4) * 4 + r;
                int n = n0 + nh + j * 16 + (lane & 15);
                if (m < M) Co[(size_t)m * kATT + n] = scale * acc[i][j][r];
            }
}

// ---------------------------------------------------------------------------
// alpha partial, register-blocked streaming: each thread owns 1 p x 5 l.
//   p1 pre-scaled by 2log2(e): sum_a v*tanh = sumV - 2*sum_a v*rcp(exp2(u*w)+1)
// grid (13, kB, kASplit); block 256 = 16 p x 16 l-groups (5 l each).
// out pre-zeroed; beta added by as==0 blocks.
// ---------------------------------------------------------------------------
__global__ __launch_bounds__(256) void alpha_kernel(
        const float* __restrict__ p1, const float* __restrict__ p2,
        const float* __restrict__ v, const float* __restrict__ beta,
        float* __restrict__ out) {
    __shared__ float vs[kAChunk];            // 512 B
    __shared__ float sred;
    const int b     = blockIdx.y;
    const int as    = blockIdx.z;
    const int aBase = as * kAChunk;
    const int p0    = blockIdx.x * 16;
    const int tid   = threadIdx.x;
    const int tp    = tid & 15;              // p lane -> 16-line u loads
    const int lg    = tid >> 4;              // l-group: l = lg*5 + j

    if (tid < kAChunk) vs[tid] = v[aBase + tid];
    __syncthreads();
    if (tid < 64) {                          // sumV of this chunk
        float s = vs[tid] + vs[tid + 64];
        #pragma unroll
        for (int off = 32; off > 0; off >>= 1)
            s += __shfl_down(s, off, 64);
        if (tid == 0) sred = s;
    }
    __syncthreads();
    const float sumV = sred;

    const int p   = p0 + tp;
    const int gr1 = b * kP + min(p, kP - 1);
    const float* pu = p1 + (size_t)gr1 * kATT + aBase;
    const float* pw = p2 + ((size_t)(b * kL + lg * kLPer)) * kATT + aBase;

    float acc[kLPer] = {};
    #pragma unroll 2
    for (int a4 = 0; a4 < kAChunk / 4; ++a4) {
        float4 u  = *(const float4*)(pu + a4 * 4);
        float4 vv = *(const float4*)&vs[a4 * 4];
        #pragma unroll
        for (int j = 0; j < kLPer; ++j) {
            float4 w = *(const float4*)(pw + (size_t)j * kATT + a4 * 4);
            acc[j] = fmaf(vv.x, __builtin_amdgcn_rcpf(__builtin_amdgcn_exp2f(u.x * w.x) + 1.0f), acc[j]);
            acc[j] = fmaf(vv.y, __builtin_amdgcn_rcpf(__builtin_amdgcn_exp2f(u.y * w.y) + 1.0f), acc[j]);
            acc[j] = fmaf(vv.z, __builtin_amdgcn_rcpf(__builtin_amdgcn_exp2f(u.z * w.z) + 1.0f), acc[j]);
            acc[j] = fmaf(vv.w, __builtin_amdgcn_rcpf(__builtin_amdgcn_exp2f(u.w * w.w) + 1.0f), acc[j]);
        }
    }
    if (p < kP) {
        const float bb = (as == 0) ? beta[0] : 0.0f;
        #pragma unroll
        for (int j = 0; j < kLPer; ++j) {
            float res = sumV - 2.0f * acc[j] + bb;
            atomicAdd(&out[((size_t)b * kL + lg * kLPer + j) * kP + p], res);
        }
    }
}

// ---------------------------------------------------------------------------
extern "C" void kernel_launch(void* const* d_in, const int* in_sizes, int n_in,
                              void* d_out, int out_size, void* d_ws, size_t ws_size,
                              hipStream_t stream) {
    const float* x1 = (const float*)d_in[0];
    const float* x2 = (const float*)d_in[1];
    const float* W1 = (const float*)d_in[2];
    const float* W2 = (const float*)d_in[3];
    const float* Wh = (const float*)d_in[4];
    const float* bh = (const float*)d_in[5];
    const float* wt = (const float*)d_in[6];
    const float* bt = (const float*)d_in[7];
    float* out = (float*)d_out;

    // workspace: v[1024] | beta pad->1088 | p2w[640*1024] | p1w[1568*1024]
    // | x1b[kM*kD1] | W1b[kATT*kD1] | x2b[kR2*320] | W2b[kATT*320]   (~20.7 MB)
    float* ws   = (float*)d_ws;
    float* v    = ws;
    float* beta = ws + 1024;
    float* p2w  = ws + 1088;
    float* p1w  = p2w + (size_t)kR2 * kATT;
    unsigned short* x1b = (unsigned short*)(p1w + (size_t)kM * kATT);
    unsigned short* W1b = x1b + (size_t)kM * kD1;
    unsigned short* x2b = W1b + (size_t)kATT * kD1;
    unsigned short* W2b = x2b + (size_t)kR2 * kD2p;

    hipMemsetAsync(ws, 0, 1088 * sizeof(float), stream);
    hipMemsetAsync(out, 0, (size_t)out_size * sizeof(float), stream);

    {   // fused casts
        int n = kM * kD1 / 4 + kATT * kD1 / 4 + kR2 * kD2p + kATT * kD2p;
        cast_all_kernel<<<dim3((n + 255) / 256), 256, 0, stream>>>(
            x1, x1b, W1, W1b, x2, x2b, W2, W2b);
    }
    vbeta_kernel<<<dim3(4, 16), 256, 0, stream>>>(Wh, wt, bh, bt, v, beta);
    gemm_all_kernel<<<dim3(kP2Blocks + kP1Blocks), 256, 0, stream>>>(
        x2b, W2b, p2w, x1b, W1b, p1w);
    alpha_kernel<<<dim3((kP + 15) / 16, kB, kASplit), 256, 0, stream>>>(
        p1w, p2w, v, beta, out);
}

// Round 7
// 154.078 us; speedup vs baseline: 1.3360x; 1.0458x over previous
//
#include <hip/hip_runtime.h>
#include <hip/hip_bf16.h>

// Problem constants
static constexpr int kB   = 8;
static constexpr int kP   = 196;
static constexpr int kL   = 80;
static constexpr int kD1  = 2048;
static constexpr int kD2  = 300;
static constexpr int kD2p = 320;       // K of p2 padded to multiple of 64
static constexpr int kATT = 1024;
static constexpr int kM   = kB * kP;   // 1568 rows of p1
static constexpr int kR2  = kB * kL;   // 640 rows of p2
static constexpr int kOut = kB * kL * kP;        // 125440 outputs
static constexpr int kASplit = 16;     // alpha: a-dim split across blocks
static constexpr int kAChunk = kATT / kASplit;   // 64
static constexpr int kLPer   = 5;      // l-values per thread (16 groups x 5 = 80)

static constexpr float kTanhScale = 2.8853900817779268f;  // 2*log2(e)

// fp32 -> bf16 round-to-nearest-even
__device__ __forceinline__ unsigned short f2bf(float x) {
    union { float f; unsigned int u; } c; c.f = x;
    unsigned int r = c.u + 0x7fffu + ((c.u >> 16) & 1u);
    return (unsigned short)(r >> 16);
}

typedef __attribute__((ext_vector_type(8))) short  bf16x8;
typedef __attribute__((ext_vector_type(4))) float  f32x4;

__device__ __forceinline__ void load_lds16(const void* g, void* l) {
    __builtin_amdgcn_global_load_lds(
        (const __attribute__((address_space(1))) void*)g,
        (__attribute__((address_space(3))) void*)l, 16, 0, 0);
}

// ---------------------------------------------------------------------------
// Fused prep: blocks [0, kCastBlocks) cast x1,W1 (float4-wide) and cast+pad
// x2,W2 (K 300->320); blocks [kCastBlocks, +64) compute v/beta partials.
// v[a] = sum_c wt[c]*Wh[c,a] (atomic-accumulated; v pre-zeroed),
// beta = dot(wt,bh) + bt.
// ---------------------------------------------------------------------------
static constexpr int kN4a = kM * kD1 / 4;      // x1 float4s   802816... /4
static constexpr int kN4b = kATT * kD1 / 4;    // W1 float4s
static constexpr int kN1  = kR2 * kD2p;        // x2b elems (padded)
static constexpr int kN2  = kATT * kD2p;       // W2b elems (padded)
static constexpr int kCastBlocks =
    (kN4a + kN4b + kN1 + kN2 + 255) / 256;     // 7264

__global__ __launch_bounds__(256) void prep_kernel(
        const float* __restrict__ x1, unsigned short* __restrict__ x1b,
        const float* __restrict__ W1, unsigned short* __restrict__ W1b,
        const float* __restrict__ x2, unsigned short* __restrict__ x2b,
        const float* __restrict__ W2, unsigned short* __restrict__ W2b,
        const float* __restrict__ Wh, const float* __restrict__ wt,
        const float* __restrict__ bh, const float* __restrict__ bt,
        float* __restrict__ v, float* __restrict__ beta) {
    if (blockIdx.x >= kCastBlocks) {           // ---- vbeta part (64 blocks)
        int bid = blockIdx.x - kCastBlocks;    // 0..63
        int ax  = bid & 3;                     // a-chunk of 256
        int c0  = (bid >> 2) * 64;             // c-slice of 64
        int a   = ax * 256 + threadIdx.x;
        float acc = 0.0f;
        #pragma unroll 8
        for (int c = c0; c < c0 + 64; ++c)
            acc = fmaf(wt[c], Wh[(size_t)c * kATT + a], acc);
        atomicAdd(&v[a], acc);
        if (ax == 0 && threadIdx.x < 64) {
            int c = c0 + threadIdx.x;
            float pb = wt[c] * bh[c];
            #pragma unroll
            for (int off = 32; off > 0; off >>= 1)
                pb += __shfl_down(pb, off, 64);
            if (threadIdx.x == 0) {
                if (c0 == 0) pb += bt[0];
                atomicAdd(beta, pb);
            }
        }
        return;
    }
    int i = blockIdx.x * 256 + threadIdx.x;    // ---- cast part
    if (i < kN4a) {
        float4 f = ((const float4*)x1)[i];
        ushort4 o = { f2bf(f.x), f2bf(f.y), f2bf(f.z), f2bf(f.w) };
        ((ushort4*)x1b)[i] = o;
    } else if ((i -= kN4a) < kN4b) {
        float4 f = ((const float4*)W1)[i];
        ushort4 o = { f2bf(f.x), f2bf(f.y), f2bf(f.z), f2bf(f.w) };
        ((ushort4*)W1b)[i] = o;
    } else if ((i -= kN4b) < kN1) {
        int r = i / kD2p, c = i - r * kD2p;
        x2b[i] = (c < kD2) ? f2bf(x2[(size_t)r * kD2 + c]) : (unsigned short)0;
    } else if ((i -= kN1) < kN2) {
        int r = i / kD2p, c = i - r * kD2p;
        W2b[i] = (c < kD2) ? f2bf(W2[(size_t)r * kD2 + c]) : (unsigned short)0;
    }
}

// ---------------------------------------------------------------------------
// Fused GEMMs (both C = scale * A·B^T, N = 1024): blocks [0,160) do p2
// (M=640, K=320), blocks [160,560) do p1 (M=1568, K=2048, scale=2log2e).
// 64x64 tile, BK=64 (16 KB LDS), 4 waves, 2x2 MFMA 16x16x32 per wave.
// ---------------------------------------------------------------------------
static constexpr int kP2Blocks = (kR2 / 64) * (kATT / 64);       // 160
static constexpr int kP1Blocks = ((kM + 63) / 64) * (kATT / 64); // 400

__global__ __launch_bounds__(256) void gemm_all_kernel(
        const unsigned short* __restrict__ x2b, const unsigned short* __restrict__ W2b,
        float* __restrict__ p2w,
        const unsigned short* __restrict__ x1b, const unsigned short* __restrict__ W1b,
        float* __restrict__ p1w) {
    __shared__ unsigned short As[64 * 64];   // 8 KB, row = 64 k-elems (128 B)
    __shared__ unsigned short Bs[64 * 64];   // 8 KB

    const unsigned short *Ab, *Bb;
    float* Co; int M, K, mx, nx; float scale;
    {
        int bid = blockIdx.x;
        if (bid < kP2Blocks) {
            Ab = x2b; Bb = W2b; Co = p2w; M = kR2; K = kD2p; scale = 1.0f;
            mx = bid % (kR2 / 64); nx = bid / (kR2 / 64);
        } else {
            int l = bid - kP2Blocks;
            Ab = x1b; Bb = W1b; Co = p1w; M = kM; K = kD1; scale = kTanhScale;
            mx = l % ((kM + 63) / 64); nx = l / ((kM + 63) / 64);
        }
    }
    const int m0   = mx * 64;
    const int n0   = nx * 64;
    const int tid  = threadIdx.x;
    const int lane = tid & 63;
    const int wv   = tid >> 6;
    const int mh   = (wv >> 1) * 32;
    const int nh   = (wv & 1) * 32;

    const int row0 = tid >> 3,         ko0 = (tid & 7) * 8;
    const int row1 = (tid + 256) >> 3, ko1 = (tid & 7) * 8;
    const int ar0 = min(m0 + row0, M - 1), ar1 = min(m0 + row1, M - 1);
    const int br0 = n0 + row0,             br1 = n0 + row1;

    f32x4 acc[2][2] = {};
    for (int k0 = 0; k0 < K; k0 += 64) {
        load_lds16(Ab + (size_t)ar0 * K + k0 + ko0, (char*)As + tid * 16);
        load_lds16(Ab + (size_t)ar1 * K + k0 + ko1, (char*)As + (tid + 256) * 16);
        load_lds16(Bb + (size_t)br0 * K + k0 + ko0, (char*)Bs + tid * 16);
        load_lds16(Bb + (size_t)br1 * K + k0 + ko1, (char*)Bs + (tid + 256) * 16);
        __syncthreads();

        #pragma unroll
        for (int kk = 0; kk < 2; ++kk) {
            bf16x8 af[2], bf[2];
            #pragma unroll
            for (int i = 0; i < 2; ++i) {
                int r = mh + i * 16 + (lane & 15);
                af[i] = *(const bf16x8*)((const char*)As + r * 128 + kk * 64 + (lane >> 4) * 16);
            }
            #pragma unroll
            for (int j = 0; j < 2; ++j) {
                int r = nh + j * 16 + (lane & 15);
                bf[j] = *(const bf16x8*)((const char*)Bs + r * 128 + kk * 64 + (lane >> 4) * 16);
            }
            #pragma unroll
            for (int i = 0; i < 2; ++i)
                #pragma unroll
                for (int j = 0; j < 2; ++j)
                    acc[i][j] = __builtin_amdgcn_mfma_f32_16x16x32_bf16(
                                    af[i], bf[j], acc[i][j], 0, 0, 0);
        }
        __syncthreads();
    }

    // C/D layout: col = lane&15, row = (lane>>4)*4 + reg   [m89/m91 verified]
    #pragma unroll
    for (int i = 0; i < 2; ++i)
        #pragma unroll
        for (int j = 0; j < 2; ++j)
            #pragma unroll
            for (int r = 0; r < 4; ++r) {
                int m = m0 + mh + i * 16 + (lane >> 4) * 4 + r;
                int n = n0 + nh + j * 16 + (lane & 15);
                if (m < M) Co[(size_t)m * kATT + n] = scale * acc[i][j][r];
            }
}

// ---------------------------------------------------------------------------
// alpha partial, register-blocked streaming, atomic-free split-K.
//   p1 pre-scaled by 2log2(e): sum_a v*tanh = sumV - 2*sum_a v*rcp(exp2(u*w)+1)
// grid (13, kB, kASplit); block 256 = 16 p x 16 l-groups (5 l each).
// Each block writes its chunk's partial to part[as][b,l,p] (plain stores).
// ---------------------------------------------------------------------------
__global__ __launch_bounds__(256) void alpha_kernel(
        const float* __restrict__ p1, const float* __restrict__ p2,
        const float* __restrict__ v, float* __restrict__ part) {
    __shared__ float vs[kAChunk];            // 256 B
    __shared__ float sred;
    const int b     = blockIdx.y;
    const int as    = blockIdx.z;
    const int aBase = as * kAChunk;
    const int p0    = blockIdx.x * 16;
    const int tid   = threadIdx.x;
    const int tp    = tid & 15;              // p lane -> 16-line u loads
    const int lg    = tid >> 4;              // l-group: l = lg*5 + j

    if (tid < kAChunk) vs[tid] = v[aBase + tid];
    __syncthreads();
    if (tid < 64) {                          // sumV of this chunk
        float s = vs[tid & (kAChunk - 1)] * ((tid < kAChunk) ? 1.0f : 0.0f);
        s = vs[tid < kAChunk ? tid : 0];
        if (tid >= kAChunk) s = 0.0f;
        #pragma unroll
        for (int off = 32; off > 0; off >>= 1)
            s += __shfl_down(s, off, 64);
        if (tid == 0) sred = s;
    }
    __syncthreads();
    const float sumV = sred;

    const int p   = p0 + tp;
    const int gr1 = b * kP + min(p, kP - 1);
    const float* pu = p1 + (size_t)gr1 * kATT + aBase;
    const float* pw = p2 + ((size_t)(b * kL + lg * kLPer)) * kATT + aBase;

    float acc[kLPer] = {};
    #pragma unroll 2
    for (int a4 = 0; a4 < kAChunk / 4; ++a4) {
        float4 u  = *(const float4*)(pu + a4 * 4);
        float4 vv = *(const float4*)&vs[a4 * 4];
        #pragma unroll
        for (int j = 0; j < kLPer; ++j) {
            float4 w = *(const float4*)(pw + (size_t)j * kATT + a4 * 4);
            acc[j] = fmaf(vv.x, __builtin_amdgcn_rcpf(__builtin_amdgcn_exp2f(u.x * w.x) + 1.0f), acc[j]);
            acc[j] = fmaf(vv.y, __builtin_amdgcn_rcpf(__builtin_amdgcn_exp2f(u.y * w.y) + 1.0f), acc[j]);
            acc[j] = fmaf(vv.z, __builtin_amdgcn_rcpf(__builtin_amdgcn_exp2f(u.z * w.z) + 1.0f), acc[j]);
            acc[j] = fmaf(vv.w, __builtin_amdgcn_rcpf(__builtin_amdgcn_exp2f(u.w * w.w) + 1.0f), acc[j]);
        }
    }
    if (p < kP) {
        float* po = part + (size_t)as * kOut + ((size_t)b * kL + lg * kLPer) * kP + p;
        #pragma unroll
        for (int j = 0; j < kLPer; ++j)
            po[(size_t)j * kP] = sumV - 2.0f * acc[j];
    }
}

// ---------------------------------------------------------------------------
// out[i] = beta + sum_s part[s][i]
// ---------------------------------------------------------------------------
__global__ __launch_bounds__(256) void reduce_kernel(
        const float* __restrict__ part, const float* __restrict__ beta,
        float* __restrict__ out) {
    int i = blockIdx.x * 256 + threadIdx.x;
    if (i < kOut) {
        float s = beta[0];
        #pragma unroll
        for (int r = 0; r < kASplit; ++r)
            s += part[(size_t)r * kOut + i];
        out[i] = s;
    }
}

// ---------------------------------------------------------------------------
extern "C" void kernel_launch(void* const* d_in, const int* in_sizes, int n_in,
                              void* d_out, int out_size, void* d_ws, size_t ws_size,
                              hipStream_t stream) {
    const float* x1 = (const float*)d_in[0];
    const float* x2 = (const float*)d_in[1];
    const float* W1 = (const float*)d_in[2];
    const float* W2 = (const float*)d_in[3];
    const float* Wh = (const float*)d_in[4];
    const float* bh = (const float*)d_in[5];
    const float* wt = (const float*)d_in[6];
    const float* bt = (const float*)d_in[7];
    float* out = (float*)d_out;

    // workspace layout (floats, then bf16, then partials):
    // v[1024] | beta pad->1088 | p2w[640*1024] | p1w[1568*1024]
    // | x1b | W1b | x2b | W2b (bf16) | part[kASplit*kOut]   (~29 MB total)
    float* ws   = (float*)d_ws;
    float* v    = ws;
    float* beta = ws + 1024;
    float* p2w  = ws + 1088;
    float* p1w  = p2w + (size_t)kR2 * kATT;
    unsigned short* x1b = (unsigned short*)(p1w + (size_t)kM * kATT);
    unsigned short* W1b = x1b + (size_t)kM * kD1;
    unsigned short* x2b = W1b + (size_t)kATT * kD1;
    unsigned short* W2b = x2b + (size_t)kR2 * kD2p;
    float* part = (float*)(W2b + (size_t)kATT * kD2p);

    hipMemsetAsync(ws, 0, 1088 * sizeof(float), stream);

    prep_kernel<<<dim3(kCastBlocks + 64), 256, 0, stream>>>(
        x1, x1b, W1, W1b, x2, x2b, W2, W2b, Wh, wt, bh, bt, v, beta);
    gemm_all_kernel<<<dim3(kP2Blocks + kP1Blocks), 256, 0, stream>>>(
        x2b, W2b, p2w, x1b, W1b, p1w);
    alpha_kernel<<<dim3((kP + 15) / 16, kB, kASplit), 256, 0, stream>>>(
        p1w, p2w, v, part);
    reduce_kernel<<<dim3((kOut + 255) / 256), 256, 0, stream>>>(part, beta, out);
}